// Round 13
// baseline (300.045 us; speedup 1.0000x reference)
//
#include <hip/hip_runtime.h>
#include <hip/hip_bf16.h>
#include <math.h>

// Problem constants
#define B_    256
#define L_    200
#define H_    256
#define MAXT  256
#define SIXH  1536
#define FOURH 1024
#define NPOS  (B_ * L_)   // 51200
#define PM    51456       // padded max compacted rows (cidx/lnp/tpos stride)

typedef __attribute__((ext_vector_type(8))) short short8;
typedef __attribute__((ext_vector_type(4))) float f32x4;

typedef __attribute__((address_space(3))) void lds_void;
typedef const __attribute__((address_space(1))) void gbl_void;

#define ASM_BAR() asm volatile("s_barrier" ::: "memory")
#define VMCNT4()  asm volatile("s_waitcnt vmcnt(4)" ::: "memory")
#define VMCNT0()  asm volatile("s_waitcnt vmcnt(0)" ::: "memory")

// ---------------------------------------------------------------------------
// conv_tables: f32 tables -> bf16 copies + per-row {sum, sumsq} stats.
// token_emb 50000 rows, tg_emb 65, g_emb 17. 1 block (64 thr) per row.
// ---------------------------------------------------------------------------
__global__ void conv_tables(const float* __restrict__ tok,
                            const float* __restrict__ tgt,
                            const float* __restrict__ gt,
                            unsigned short* __restrict__ tokb,
                            unsigned short* __restrict__ tgb,
                            unsigned short* __restrict__ gb,
                            float2* __restrict__ tok_st,
                            float2* __restrict__ tg_st,
                            float2* __restrict__ g_st) {
  int bid = blockIdx.x, t = threadIdx.x;
  const float* src; unsigned short* dst; float2* st; int row;
  if (bid < 50000)      { src = tok; dst = tokb; st = tok_st; row = bid; }
  else if (bid < 50065) { src = tgt; dst = tgb;  st = tg_st;  row = bid - 50000; }
  else                  { src = gt;  dst = gb;   st = g_st;   row = bid - 50065; }

  float4 v = ((const float4*)(src + (size_t)row * 256))[t];
  __hip_bfloat16 h0 = __float2bfloat16(v.x), h1 = __float2bfloat16(v.y);
  __hip_bfloat16 h2 = __float2bfloat16(v.z), h3 = __float2bfloat16(v.w);
  ushort4 o;
  o.x = *(unsigned short*)&h0; o.y = *(unsigned short*)&h1;
  o.z = *(unsigned short*)&h2; o.w = *(unsigned short*)&h3;
  ((ushort4*)(dst + (size_t)row * 256))[t] = o;

  float s = v.x + v.y + v.z + v.w;
  float q = v.x * v.x + v.y * v.y + v.z * v.z + v.w * v.w;
#pragma unroll
  for (int off = 32; off; off >>= 1) {
    s += __shfl_down(s, off);
    q += __shfl_down(q, off);
  }
  if (t == 0) st[row] = make_float2(s, q);
}

// ---------------------------------------------------------------------------
// transpose_both: w1 [1536][1024] -> w1t [1024][1536] bf16 with GAMMA FOLDED
// (w1t[n][k] = bf16(gamma[k] * w1[k][n])); w2 -> w2t plain.
// ---------------------------------------------------------------------------
__global__ void transpose_both(const float* __restrict__ w1,
                               __hip_bfloat16* __restrict__ w1t,
                               const float* __restrict__ w2,
                               __hip_bfloat16* __restrict__ w2t,
                               const float* __restrict__ gamma) {
  __shared__ float tile[32][33];
  int id = blockIdx.x;
  const float* in; __hip_bfloat16* out; int R, C, tc, tr;
  bool isw1 = id < 1536;
  if (isw1) {
    in = w1; out = w1t; R = 1536; C = 1024; tc = id & 31; tr = id >> 5;
  } else {
    int j = id - 1536;
    in = w2; out = w2t; R = 1024; C = 256; tc = j & 7; tr = j >> 3;
  }
  int tx = threadIdx.x & 31, ty = threadIdx.x >> 5;
#pragma unroll
  for (int i = 0; i < 4; i++)
    tile[ty + i * 8][tx] = in[(size_t)(tr * 32 + ty + i * 8) * C + tc * 32 + tx];
  __syncthreads();
  float gm = isw1 ? gamma[tr * 32 + tx] : 1.0f;  // ocol = k index
#pragma unroll
  for (int i = 0; i < 4; i++)
    out[(size_t)(tc * 32 + ty + i * 8) * R + tr * 32 + tx] =
        __float2bfloat16(tile[tx][ty + i * 8] * gm);
}

// ---------------------------------------------------------------------------
// colstats: G[n] = sum_k gamma[k]*w1[k][n]; U[n] = sum_k beta[k]*w1[k][n].
// 4 blocks x 1024 thr (256 n-lanes x 4 k-quarters), LDS reduce.
// ---------------------------------------------------------------------------
__global__ void colstats(const float* __restrict__ w1,
                         const float* __restrict__ gamma,
                         const float* __restrict__ beta,
                         float* __restrict__ Gn, float* __restrict__ Un) {
  int t = threadIdx.x & 255;
  int kq = threadIdx.x >> 8;  // 0..3
  int n = blockIdx.x * 256 + t;
  float G = 0.f, U = 0.f;
  int k0 = kq * 384;
  for (int k = k0; k < k0 + 384; k++) {
    float w = w1[(size_t)k * 1024 + n];
    G = fmaf(gamma[k], w, G);
    U = fmaf(beta[k], w, U);
  }
  __shared__ float sG[4][256], sU[4][256];
  sG[kq][t] = G; sU[kq][t] = U;
  __syncthreads();
  if (kq == 0) {
    Gn[n] = sG[0][t] + sG[1][t] + sG[2][t] + sG[3][t];
    Un[n] = sU[0][t] + sU[1][t] + sU[2][t] + sU[3][t];
  }
}

// ---------------------------------------------------------------------------
// fused_pre: offsets prefix-sum, tpos scatter map, compacted cidx[6][row],
// per-row LN params lnp[row]={rstd, mu*rstd}, pad-row defaults.
// ---------------------------------------------------------------------------
__global__ void fused_pre(const int* __restrict__ lengths,
                          const int* __restrict__ tok0,
                          const int* __restrict__ tok1,
                          const int* __restrict__ tok2,
                          const int* __restrict__ tok3,
                          const int* __restrict__ tgap,
                          const int* __restrict__ gids,
                          const float2* __restrict__ tok_st,
                          const float2* __restrict__ tg_st,
                          const float2* __restrict__ g_st,
                          int* __restrict__ offsets,
                          int* __restrict__ tpos,
                          int* __restrict__ cidx,
                          float2* __restrict__ lnp) {
  int b = blockIdx.x, t = threadIdx.x;
  int lane = t & 63, wv = t >> 6;

  // block-local prefix sum over all 256 lengths
  int len_t = lengths[t];
  int s = len_t;
#pragma unroll
  for (int o = 1; o < 64; o <<= 1) {
    int v = __shfl_up(s, o);
    if (lane >= o) s += v;
  }
  __shared__ int wsum[4];
  __shared__ int all_off[257];
  if (lane == 63) wsum[wv] = s;
  __syncthreads();
  int pre = 0;
#pragma unroll
  for (int k = 0; k < 4; k++)
    if (k < wv) pre += wsum[k];
  s += pre;
  all_off[t] = s - len_t;
  if (t == 255) all_off[256] = s;
  __syncthreads();

  int base = all_off[b];
  int total = all_off[256];
  if (t == 0) {
    offsets[b] = base;
    if (b == 0) offsets[B_] = total;
  }

  int len = lengths[b];

  // per-position: cidx + LN params (t == l, len <= 200 < 256)
  if (t < len) {
    int pos = b * L_ + t;
    int row = base + t;
    int i0 = tok0[pos], i1 = tok1[pos], i2 = tok2[pos], i3 = tok3[pos];
    int i4 = min(max(tgap[pos], 0), 64);
    int i5 = gids[pos];
    cidx[row] = i0;
    cidx[PM + row] = i1;
    cidx[2 * PM + row] = i2;
    cidx[3 * PM + row] = i3;
    cidx[4 * PM + row] = i4;
    cidx[5 * PM + row] = i5;
    float2 a0 = tok_st[i0], a1 = tok_st[i1], a2 = tok_st[i2], a3 = tok_st[i3];
    float2 a4 = tg_st[i4], a5 = g_st[i5];
    float S = a0.x + a1.x + a2.x + a3.x + a4.x + a5.x;
    float Q = a0.y + a1.y + a2.y + a3.y + a4.y + a5.y;
    float mu = S * (1.0f / 1536.0f);
    float var = Q * (1.0f / 1536.0f) - mu * mu;
    float rstd = rsqrtf(var + 1e-5f);
    lnp[row] = make_float2(rstd, mu * rstd);
  }

  // tpos for batch b (serial scan; g preloaded)
  __shared__ int g[L_];
  for (int l = t; l < len; l += 256) g[l] = gids[b * L_ + l];
  __syncthreads();
  if (t == 0) {
    int nsep = 0;
    for (int l = 0; l + 1 < len; l++)
      if (g[l] != g[l + 1]) nsep++;
    int tot = len + nsep;
    int off = MAXT - tot;
    int sb = 0;
    for (int l = 0; l < len; l++) {
      int ti = off + l + sb;
      tpos[base + l] = (ti >= 0) ? (b * MAXT + ti) : -1;
      if (l + 1 < len && g[l] != g[l + 1]) sb++;
    }
    // pad row defaults (row total+b): safe table row 0, lnp = 0
    int padded = (total + 255) & ~255;
    int prow = total + b;
    if (prow < padded) {
#pragma unroll
      for (int j = 0; j < 6; j++) cidx[j * PM + prow] = 0;
      lnp[prow] = make_float2(0.f, 0.f);
    }
  }
}

// ---------------------------------------------------------------------------
// GEMM1 fused (R13): R9-verified schedule (persistent, XCD-sibling-grouped,
// 256x256, BK=64, 8 waves, 2-barrier K-loop, vmcnt(4), XOR-swizzled LDS),
// with A staged DIRECTLY from the bf16 embedding tables (x eliminated):
//   col range of K-tile kt lies in table j = kt>>2 (static under full
//   unroll), source = tab_j + cidx[j][row]*512B + ((kt&3)*128 + h*64 + 2*scol).
// Epilogue applies the folded LN: h = silu(acc*rstd - mu*rstd*G[col]
//   + U[col] + b1[col]).
// ---------------------------------------------------------------------------
__global__ __launch_bounds__(512, 2)
void gemm1_fused(const unsigned short* __restrict__ tokb,
                 const unsigned short* __restrict__ tgb,
                 const unsigned short* __restrict__ gb,
                 const int* __restrict__ cidx,
                 const float2* __restrict__ lnp,
                 const __hip_bfloat16* __restrict__ Bt,
                 const float* __restrict__ Gn,
                 const float* __restrict__ Un,
                 const float* __restrict__ bias,
                 __hip_bfloat16* __restrict__ out,
                 const int* __restrict__ total_ptr) {
  constexpr int K = SIXH;     // 1536
  constexpr int NT = K / 64;  // 24 K-tiles
  constexpr int N = FOURH;    // 1024

  extern __shared__ __align__(16) char lds[];

  int total = total_ptr[0];
  int padded = (total + 255) & ~255;
  int num_mt = padded >> 8;

  int bid = blockIdx.x;        // 0..255
  int xcd = bid & 7;
  int slot = bid >> 3;         // 0..31
  int nt = slot & 3;           // 0..3
  int mtb = slot >> 2;         // 0..7
  int n0 = nt * 256;

  int tid = threadIdx.x;
  int lane = tid & 63;
  int w = tid >> 6;
  int wave_m = w >> 2;
  int wave_n = w & 3;

  int r15 = lane & 15, g = lane >> 4;
  int slot_r = (((r15 & 1) << 2) | g) ^ (r15 >> 1);
  int lane_off = (r15 >> 1) * 128 + slot_r * 16;

  int s0 = (tid & 7) ^ ((tid >> 3) & 7);
  int scol = (s0 & 3) * 8;
  int row0 = ((tid >> 3) << 1) + (s0 >> 2);
  int ldst0 = w * 1024;

  // per-col epilogue constants (independent of mt)
  float Gc[4], Uc[4];
#pragma unroll
  for (int ni = 0; ni < 4; ni++) {
    int col = n0 + wave_n * 64 + ni * 16 + r15;
    Gc[ni] = Gn[col];
    Uc[ni] = Un[col] + bias[col];
  }

#define REGA(d, h) (lds + (d) * 65536 + (h) * 16384)
#define REGB(d, h) (lds + (d) * 65536 + 32768 + (h) * 16384)

  // A stage from tables: kc -> table j (static after unroll), per-thread idx
#define STAGE_A(kc, h, rb)                                                     \
  do {                                                                         \
    const unsigned short* _tb =                                                \
        ((kc) >> 2) < 4 ? tokb : (((kc) >> 2) == 4 ? tgb : gb);                \
    size_t _off = (size_t)(((kc) & 3) * 128 + (h) * 64 + scol * 2);            \
    __builtin_amdgcn_global_load_lds(                                          \
        (gbl_void*)((const char*)_tb + (size_t)c0[(kc) >> 2] * 512 + _off),    \
        (lds_void*)((rb) + ldst0), 16, 0, 0);                                  \
    __builtin_amdgcn_global_load_lds(                                          \
        (gbl_void*)((const char*)_tb + (size_t)c1[(kc) >> 2] * 512 + _off),    \
        (lds_void*)((rb) + 8192 + ldst0), 16, 0, 0);                           \
  } while (0)

#define STAGE_B(kt, h, rb)                                                     \
  do {                                                                         \
    __builtin_amdgcn_global_load_lds(                                          \
        (gbl_void*)(Bt + (size_t)(n0 + row0) * K + (kt) * 64 + (h) * 32 +      \
                    scol),                                                     \
        (lds_void*)((rb) + ldst0), 16, 0, 0);                                  \
    __builtin_amdgcn_global_load_lds(                                          \
        (gbl_void*)(Bt + (size_t)(n0 + row0 + 128) * K + (kt) * 64 +           \
                    (h) * 32 + scol),                                          \
        (lds_void*)((rb) + 8192 + ldst0), 16, 0, 0);                           \
  } while (0)

  for (int mt = xcd + 8 * mtb; mt < num_mt; mt += 64) {
    int m0 = mt * 256;

    // per-thread table indices for the two staged rows (static j indexing)
    int c0[6], c1[6];
#pragma unroll
    for (int j = 0; j < 6; j++) {
      c0[j] = cidx[j * PM + m0 + row0];
      c1[j] = cidx[j * PM + m0 + row0 + 128];
    }

    f32x4 acc[8][4] = {};

    STAGE_A(0, 0, REGA(0, 0));
    STAGE_B(0, 0, REGB(0, 0));
    STAGE_A(0, 1, REGA(0, 1));
    STAGE_B(0, 1, REGB(0, 1));
    STAGE_A(1, 0, REGA(1, 0));
    STAGE_B(1, 0, REGB(1, 0));
    VMCNT4();
    ASM_BAR();

#pragma unroll
    for (int kt = 0; kt < NT; ++kt) {
      int d = kt & 1;
      int kc1 = (kt + 1 < NT) ? kt + 1 : NT - 1;
      int kc2 = (kt + 2 < NT) ? kt + 2 : NT - 1;
      char* A0 = REGA(d, 0); char* A1 = REGA(d, 1);
      char* B0 = REGB(d, 0); char* B1 = REGB(d, 1);
      char* An1 = REGA(d ^ 1, 1);
      char* Bn1 = REGB(d ^ 1, 1);

      short8 a[4], b[4];

      // ======== first half: kh0 (reads A0/B0; stages next-dbuf kh1) ========
#pragma unroll
      for (int ni = 0; ni < 4; ni++)
        b[ni] = *(const short8*)(B0 + (wave_n * 64 + ni * 16) * 64 + lane_off);
#pragma unroll
      for (int j = 0; j < 4; j++)
        a[j] = *(const short8*)(A0 + (wave_m * 128 + j * 16) * 64 + lane_off);
      STAGE_A(kc1, 1, An1);
      __builtin_amdgcn_s_setprio(1);
#pragma unroll
      for (int j = 0; j < 4; j++)
#pragma unroll
        for (int ni = 0; ni < 4; ni++)
          acc[j][ni] = __builtin_amdgcn_mfma_f32_16x16x32_bf16(a[j], b[ni],
                                                               acc[j][ni], 0, 0, 0);
      __builtin_amdgcn_s_setprio(0);
#pragma unroll
      for (int j = 0; j < 4; j++)
        a[j] = *(const short8*)(A0 + (wave_m * 128 + (4 + j) * 16) * 64 + lane_off);
      STAGE_B(kc1, 1, Bn1);
      __builtin_amdgcn_s_setprio(1);
#pragma unroll
      for (int j = 0; j < 4; j++)
#pragma unroll
        for (int ni = 0; ni < 4; ni++)
          acc[4 + j][ni] = __builtin_amdgcn_mfma_f32_16x16x32_bf16(
              a[j], b[ni], acc[4 + j][ni], 0, 0, 0);
      __builtin_amdgcn_s_setprio(0);
      ASM_BAR();  // bar_mid

      // ======== second half: kh1 (reads A1/B1; stages this-dbuf kh0) =======
#pragma unroll
      for (int ni = 0; ni < 4; ni++)
        b[ni] = *(const short8*)(B1 + (wave_n * 64 + ni * 16) * 64 + lane_off);
#pragma unroll
      for (int j = 0; j < 4; j++)
        a[j] = *(const short8*)(A1 + (wave_m * 128 + j * 16) * 64 + lane_off);
      STAGE_A(kc2, 0, A0);
      __builtin_amdgcn_s_setprio(1);
#pragma unroll
      for (int j = 0; j < 4; j++)
#pragma unroll
        for (int ni = 0; ni < 4; ni++)
          acc[j][ni] = __builtin_amdgcn_mfma_f32_16x16x32_bf16(a[j], b[ni],
                                                               acc[j][ni], 0, 0, 0);
      __builtin_amdgcn_s_setprio(0);
#pragma unroll
      for (int j = 0; j < 4; j++)
        a[j] = *(const short8*)(A1 + (wave_m * 128 + (4 + j) * 16) * 64 + lane_off);
      STAGE_B(kc2, 0, B0);
      __builtin_amdgcn_s_setprio(1);
#pragma unroll
      for (int j = 0; j < 4; j++)
#pragma unroll
        for (int ni = 0; ni < 4; ni++)
          acc[4 + j][ni] = __builtin_amdgcn_mfma_f32_16x16x32_bf16(
              a[j], b[ni], acc[4 + j][ni], 0, 0, 0);
      __builtin_amdgcn_s_setprio(0);
      VMCNT4();
      ASM_BAR();  // bar_end
    }
    VMCNT0();

    // epilogue: folded LN + bias + silu
    int r0g = g * 4;
#pragma unroll
    for (int mi = 0; mi < 8; mi++)
#pragma unroll
      for (int r = 0; r < 4; r++) {
        int row = m0 + wave_m * 128 + mi * 16 + r0g + r;
        float2 lp = lnp[row];
#pragma unroll
        for (int ni = 0; ni < 4; ni++) {
          int col = n0 + wave_n * 64 + ni * 16 + r15;
          float v = acc[mi][ni][r] * lp.x - lp.y * Gc[ni] + Uc[ni];
          v = v / (1.0f + __expf(-v));  // silu
          out[(size_t)row * N + col] = __float2bfloat16(v);
        }
      }
  }
#undef STAGE_A
#undef STAGE_B
#undef REGA
#undef REGB
}

// ---------------------------------------------------------------------------
// GEMM2 wide (unchanged from R12): 128 rows x full N=256, 8 waves of 64x64,
// fused scatter epilogue into d_out.
// ---------------------------------------------------------------------------
__global__ __launch_bounds__(512, 2)
void gemm2_wide(const __hip_bfloat16* __restrict__ A,
                const __hip_bfloat16* __restrict__ Bt,
                const float* __restrict__ bias,
                const int* __restrict__ tpos,
                const float* __restrict__ pos_emb,
                float* __restrict__ out,
                const int* __restrict__ total_ptr) {
  constexpr int K = FOURH;  // 1024
  int m0 = blockIdx.x * 128;
  int total = total_ptr[0];
  int padded = (total + 127) & ~127;
  if (m0 >= padded) return;

  __shared__ __hip_bfloat16 As[128 * 64];  // 16KB
  __shared__ __hip_bfloat16 Bs[256 * 64];  // 32KB
  int tid = threadIdx.x;
  int lane = tid & 63, w = tid >> 6;
  int wave_m = w >> 2;  // 0..1
  int wave_n = w & 3;   // 0..3
  int wm = wave_m * 64, wn = wave_n * 64;

  int srow = lane >> 3;
  int scol = (lane & 7) * 8;
  int r15 = lane & 15, g = lane >> 4;

  f32x4 acc[4][4] = {};

  for (int k0 = 0; k0 < K; k0 += 64) {
#pragma unroll
    for (int i = 0; i < 2; i++) {
      int c = w * 2 + i;
      int row = c * 8 + srow;
      __builtin_amdgcn_global_load_lds(
          (gbl_void*)&A[(size_t)(m0 + row) * K + k0 + scol],
          (lds_void*)(As + c * 512), 16, 0, 0);
    }
#pragma unroll
    for (int i = 0; i < 4; i++) {
      int c = w * 4 + i;
      int row = c * 8 + srow;
      __builtin_amdgcn_global_load_lds(
          (gbl_void*)&Bt[(size_t)row * K + k0 + scol],
          (lds_void*)(Bs + c * 512), 16, 0, 0);
    }
    __syncthreads();
#pragma unroll
    for (int kk = 0; kk < 64; kk += 32) {
      short8 a[4], bb[4];
#pragma unroll
      for (int m = 0; m < 4; m++)
        a[m] = *(const short8*)&As[(wm + m * 16 + r15) * 64 + kk + 8 * g];
#pragma unroll
      for (int n = 0; n < 4; n++)
        bb[n] = *(const short8*)&Bs[(wn + n * 16 + r15) * 64 + kk + 8 * g];
#pragma unroll
      for (int m = 0; m < 4; m++)
#pragma unroll
        for (int n = 0; n < 4; n++)
          acc[m][n] = __builtin_amdgcn_mfma_f32_16x16x32_bf16(a[m], bb[n],
                                                              acc[m][n], 0, 0, 0);
    }
    __syncthreads();
  }

  int r0 = g * 4;
#pragma unroll
  for (int m = 0; m < 4; m++) {
#pragma unroll
    for (int r = 0; r < 4; r++) {
      int row = m0 + wm + m * 16 + r0 + r;
      if (row >= total) continue;
      int pa = tpos[row];
      if (pa < 0) continue;
      int p = pa & (MAXT - 1);
#pragma unroll
      for (int n = 0; n < 4; n++) {
        int col = wn + n * 16 + r15;
        float v = acc[m][n][r] + bias[col] + pos_emb[p * H_ + col];
        out[(size_t)pa * H_ + col] = v;
      }
    }
  }
}

// ---------------------------------------------------------------------------
// merge2: sep rows (sep_token + pos_emb), zero-fill empty positions, mm.
// ---------------------------------------------------------------------------
__global__ void merge2_kernel(const int* __restrict__ gids,
                              const int* __restrict__ lengths,
                              const float* __restrict__ sep_token,
                              const float* __restrict__ pos_emb,
                              float* __restrict__ out) {
  int b = blockIdx.x, t = threadIdx.x;
  __shared__ signed char src[MAXT];
  __shared__ int g[L_];
  __shared__ int sh_total;
  int len = lengths[b];
  src[t] = 0;
  for (int l = t; l < len; l += 256) g[l] = gids[b * L_ + l];
  __syncthreads();
  if (t == 0) {
    int nsep = 0;
    for (int l = 0; l + 1 < len; l++)
      if (g[l] != g[l + 1]) nsep++;
    int total = len + nsep;
    sh_total = total;
    int off = MAXT - total;
    int sb = 0;
    for (int l = 0; l < len; l++) {
      int ti = off + l + sb;
      if (ti >= 0) src[ti] = 2;
      if (l + 1 < len && g[l] != g[l + 1]) {
        if (ti + 1 >= 0) src[ti + 1] = 1;
        sb++;
      }
    }
  }
  __syncthreads();
  int total = sh_total;
  int mlen = min(total, MAXT);

  int q = t >> 6, lane = t & 63, c4 = lane * 4;
  float4 sep4 = *(const float4*)&sep_token[c4];
  float* orow = out + (size_t)b * MAXT * H_;
  for (int p0 = 0; p0 < MAXT; p0 += 4) {
    int p = p0 + q;
    int s = src[p];
    if (s == 2) continue;
    float4 v;
    if (s == 1) {
      float4 pe = *(const float4*)&pos_emb[p * H_ + c4];
      v.x = sep4.x + pe.x; v.y = sep4.y + pe.y;
      v.z = sep4.z + pe.z; v.w = sep4.w + pe.w;
    } else {
      v.x = 0.f; v.y = 0.f; v.z = 0.f; v.w = 0.f;
    }
    *(float4*)&orow[(size_t)p * H_ + c4] = v;
  }
  float* mm = out + (size_t)B_ * MAXT * H_;
  mm[b * MAXT + t] = (t >= MAXT - mlen) ? 1.0f : 0.0f;
}

// ---------------------------------------------------------------------------
// launch
// ---------------------------------------------------------------------------
extern "C" void kernel_launch(void* const* d_in, const int* in_sizes, int n_in,
                              void* d_out, int out_size, void* d_ws,
                              size_t ws_size, hipStream_t stream) {
  const int* tok0 = (const int*)d_in[0];
  const int* tok1 = (const int*)d_in[1];
  const int* tok2 = (const int*)d_in[2];
  const int* tok3 = (const int*)d_in[3];
  const int* tgap = (const int*)d_in[4];
  const int* gid  = (const int*)d_in[5];
  const int* lengths = (const int*)d_in[6];
  const float* token_emb = (const float*)d_in[7];
  const float* gamma = (const float*)d_in[8];
  const float* beta  = (const float*)d_in[9];
  const float* w1 = (const float*)d_in[10];
  const float* b1 = (const float*)d_in[11];
  const float* w2 = (const float*)d_in[12];
  const float* b2 = (const float*)d_in[13];
  const float* tg_emb = (const float*)d_in[14];
  const float* g_emb  = (const float*)d_in[15];
  const float* pos_emb = (const float*)d_in[16];
  const float* sep_tok = (const float*)d_in[17];

  // workspace layout (bytes) — x ELIMINATED:
  //   h      bf16 [<=51200][1024] @ 0          (104,857,600)
  //   w1t    bf16 [1024][1536]    @ 104857600  (  3,145,728)
  //   w2t    bf16 [256][1024]     @ 108003328  (    524,288)
  //   tokb   bf16 [50000][256]    @ 108527616  ( 25,600,000)
  //   tgb    bf16 [65][256]       @ 134127616  (     33,280)
  //   gb     bf16 [17][256]       @ 134160896  (      8,704)
  //   tok_st f2   [50000]         @ 134169600  (    400,000)
  //   tg_st  f2   [65]            @ 134569600  (        520) -> pad
  //   g_st   f2   [17]            @ 134570240  (        136) -> pad
  //   offsets int [257]           @ 134570496  (      1,028) -> pad
  //   tpos   int  [PM]            @ 134571776  (    205,824)
  //   cidx   int  [6][PM]         @ 134777600  (  1,234,944)
  //   lnp    f2   [PM]            @ 136012544  (    411,648)
  //   Gn     f32  [1024]          @ 136424192  (      4,096)
  //   Un     f32  [1024]          @ 136428288  (      4,096)
  const size_t NEEDED = 136432384;
  if (ws_size < NEEDED) return;

  char* ws = (char*)d_ws;
  __hip_bfloat16* h = (__hip_bfloat16*)ws;
  __hip_bfloat16* w1t = (__hip_bfloat16*)(ws + 104857600);
  __hip_bfloat16* w2t = (__hip_bfloat16*)(ws + 108003328);
  unsigned short* tokb = (unsigned short*)(ws + 108527616);
  unsigned short* tgb = (unsigned short*)(ws + 134127616);
  unsigned short* gb = (unsigned short*)(ws + 134160896);
  float2* tok_st = (float2*)(ws + 134169600);
  float2* tg_st = (float2*)(ws + 134569600);
  float2* g_st = (float2*)(ws + 134570240);
  int* offsets = (int*)(ws + 134570496);
  int* tpos = (int*)(ws + 134571776);
  int* cidx = (int*)(ws + 134777600);
  float2* lnp = (float2*)(ws + 136012544);
  float* Gn = (float*)(ws + 136424192);
  float* Un = (float*)(ws + 136428288);

  conv_tables<<<50082, 64, 0, stream>>>(token_emb, tg_emb, g_emb, tokb, tgb,
                                        gb, tok_st, tg_st, g_st);

  transpose_both<<<1792, 256, 0, stream>>>(w1, w1t, w2, w2t, gamma);

  colstats<<<4, 1024, 0, stream>>>(w1, gamma, beta, Gn, Un);

  fused_pre<<<B_, 256, 0, stream>>>(lengths, tok0, tok1, tok2, tok3, tgap,
                                    gid, tok_st, tg_st, g_st, offsets, tpos,
                                    cidx, lnp);

  hipFuncSetAttribute((const void*)gemm1_fused,
                      hipFuncAttributeMaxDynamicSharedMemorySize, 131072);
  gemm1_fused<<<256, 512, 131072, stream>>>(tokb, tgb, gb, cidx, lnp, w1t, Gn,
                                            Un, b1, h, offsets + B_);

  gemm2_wide<<<NPOS / 128, 512, 0, stream>>>(h, w2t, b2, tpos, pos_emb,
                                             (float*)d_out, offsets + B_);

  merge2_kernel<<<B_, 256, 0, stream>>>(gid, lengths, sep_tok, pos_emb,
                                        (float*)d_out);
}

// Round 14
// 231.000 us; speedup vs baseline: 1.2989x; 1.2989x over previous
//
#include <hip/hip_runtime.h>
#include <hip/hip_bf16.h>
#include <math.h>

// Problem constants
#define B_    256
#define L_    200
#define H_    256
#define MAXT  256
#define SIXH  1536
#define FOURH 1024
#define NPOS  (B_ * L_)   // 51200

typedef __attribute__((ext_vector_type(8))) short short8;
typedef __attribute__((ext_vector_type(4))) float f32x4;

typedef __attribute__((address_space(3))) void lds_void;
typedef const __attribute__((address_space(1))) void gbl_void;

#define ASM_BAR() asm volatile("s_barrier" ::: "memory")
#define VMCNT4()  asm volatile("s_waitcnt vmcnt(4)" ::: "memory")
#define VMCNT0()  asm volatile("s_waitcnt vmcnt(0)" ::: "memory")

// ---------------------------------------------------------------------------
// fused_pre_tr: ONE launch, 2048 blocks x 256 threads.
//   blocks 0..255   : prefix-sum offsets, tpos scatter map, zero-pad x rows
//   blocks 256..2047: weight transpose+bf16 (w1 -> w1t, w2 -> w2t)
// ---------------------------------------------------------------------------
__global__ void fused_pre_tr(const int* __restrict__ lengths,
                             const int* __restrict__ gids,
                             int* __restrict__ offsets,
                             int* __restrict__ tpos,
                             __hip_bfloat16* __restrict__ x,
                             const float* __restrict__ w1,
                             __hip_bfloat16* __restrict__ w1t,
                             const float* __restrict__ w2,
                             __hip_bfloat16* __restrict__ w2t) {
  int bid = blockIdx.x;
  int t = threadIdx.x;

  if (bid >= 256) {
    // ---- transpose part ----
    __shared__ float tile[32][33];
    int id = bid - 256;
    const float* in; __hip_bfloat16* out; int R, C, tc, tr;
    if (id < 1536) {
      in = w1; out = w1t; R = 1536; C = 1024; tc = id & 31; tr = id >> 5;
    } else {
      int j = id - 1536;
      in = w2; out = w2t; R = 1024; C = 256; tc = j & 7; tr = j >> 3;
    }
    int tx = t & 31, ty = t >> 5;
#pragma unroll
    for (int i = 0; i < 4; i++)
      tile[ty + i * 8][tx] =
          in[(size_t)(tr * 32 + ty + i * 8) * C + tc * 32 + tx];
    __syncthreads();
#pragma unroll
    for (int i = 0; i < 4; i++)
      out[(size_t)(tc * 32 + ty + i * 8) * R + tr * 32 + tx] =
          __float2bfloat16(tile[tx][ty + i * 8]);
    return;
  }

  // ---- pre part (block b = bid) ----
  int b = bid;
  int lane = t & 63, wv = t >> 6;

  int len_t = lengths[t];
  int s = len_t;
#pragma unroll
  for (int o = 1; o < 64; o <<= 1) {
    int v = __shfl_up(s, o);
    if (lane >= o) s += v;
  }
  __shared__ int wsum[4];
  __shared__ int all_off[257];
  if (lane == 63) wsum[wv] = s;
  __syncthreads();
  int pre = 0;
#pragma unroll
  for (int k = 0; k < 4; k++)
    if (k < wv) pre += wsum[k];
  s += pre;
  all_off[t] = s - len_t;
  if (t == 255) all_off[256] = s;
  __syncthreads();

  int base = all_off[b];
  int total = all_off[256];
  if (t == 0) {
    offsets[b] = base;
    if (b == 0) offsets[B_] = total;
  }

  // tpos for batch b
  __shared__ int g[L_];
  int len = lengths[b];
  for (int l = t; l < len; l += 256) g[l] = gids[b * L_ + l];
  __syncthreads();
  if (t == 0) {
    int nsep = 0;
    for (int l = 0; l + 1 < len; l++)
      if (g[l] != g[l + 1]) nsep++;
    int tot = len + nsep;
    int off = MAXT - tot;
    int sb = 0;
    for (int l = 0; l < len; l++) {
      int ti = off + l + sb;
      tpos[base + l] = (ti >= 0) ? (b * MAXT + ti) : -1;
      if (l + 1 < len && g[l] != g[l + 1]) sb++;
    }
  }

  // zero-pad x row (total + b) if within padded range
  int padded = (total + 255) & ~255;
  int row = total + b;
  if (row < padded) {
#pragma unroll
    for (int j = 0; j < 6; j++)
      x[(size_t)row * SIXH + j * 256 + t] = __float2bfloat16(0.0f);
  }
}

// ---------------------------------------------------------------------------
// Fused embedding gather + concat + LayerNorm -> x bf16 [row][1536]
// R14: 192 threads (3 waves); thread handles 8 channels of table
// j = wv*2 + (lane>>5); two float4 loads, one 16B bf16x8 store (G13).
// ---------------------------------------------------------------------------
__global__ void embed_ln_kernel(const int* __restrict__ tok0,
                                const int* __restrict__ tok1,
                                const int* __restrict__ tok2,
                                const int* __restrict__ tok3,
                                const int* __restrict__ tgap,
                                const int* __restrict__ gid,
                                const int* __restrict__ lengths,
                                const int* __restrict__ offsets,
                                const float* __restrict__ token_emb,
                                const float* __restrict__ tg_emb,
                                const float* __restrict__ g_emb,
                                const float* __restrict__ gamma,
                                const float* __restrict__ beta,
                                __hip_bfloat16* __restrict__ xout) {
  int l = blockIdx.x, b = blockIdx.y;
  if (l >= lengths[b]) return;
  int pos = b * L_ + l;
  int row = offsets[b] + l;
  int t = threadIdx.x;        // 0..191
  int wv = t >> 6;            // 0..2
  int lane = t & 63;
  int j = wv * 2 + (lane >> 5);  // table 0..5
  int c8 = (lane & 31) * 8;      // channel base within table

  const float* tab;
  int idx;
  if (j == 0)      { tab = token_emb; idx = tok0[pos]; }
  else if (j == 1) { tab = token_emb; idx = tok1[pos]; }
  else if (j == 2) { tab = token_emb; idx = tok2[pos]; }
  else if (j == 3) { tab = token_emb; idx = tok3[pos]; }
  else if (j == 4) { tab = tg_emb;    idx = min(max(tgap[pos], 0), 64); }
  else             { tab = g_emb;     idx = gid[pos]; }

  const float* src = tab + (size_t)idx * H_ + c8;
  float4 v0 = *(const float4*)src;
  float4 v1 = *(const float4*)(src + 4);

  float s = v0.x + v0.y + v0.z + v0.w + v1.x + v1.y + v1.z + v1.w;
  float q = v0.x * v0.x + v0.y * v0.y + v0.z * v0.z + v0.w * v0.w +
            v1.x * v1.x + v1.y * v1.y + v1.z * v1.z + v1.w * v1.w;
#pragma unroll
  for (int o = 32; o; o >>= 1) { s += __shfl_down(s, o); q += __shfl_down(q, o); }
  __shared__ float ps[3], pq[3];
  if (lane == 0) { ps[wv] = s; pq[wv] = q; }
  __syncthreads();
  float ts = ps[0] + ps[1] + ps[2];
  float tq = pq[0] + pq[1] + pq[2];
  float mu = ts * (1.0f / 1536.0f);
  float var = tq * (1.0f / 1536.0f) - mu * mu;
  float rstd = rsqrtf(var + 1e-5f);

  int cbase = j * 256 + c8;
  float4 gm0 = *(const float4*)&gamma[cbase];
  float4 gm1 = *(const float4*)&gamma[cbase + 4];
  float4 bt0 = *(const float4*)&beta[cbase];
  float4 bt1 = *(const float4*)&beta[cbase + 4];

  float y[8];
  y[0] = (v0.x - mu) * rstd * gm0.x + bt0.x;
  y[1] = (v0.y - mu) * rstd * gm0.y + bt0.y;
  y[2] = (v0.z - mu) * rstd * gm0.z + bt0.z;
  y[3] = (v0.w - mu) * rstd * gm0.w + bt0.w;
  y[4] = (v1.x - mu) * rstd * gm1.x + bt1.x;
  y[5] = (v1.y - mu) * rstd * gm1.y + bt1.y;
  y[6] = (v1.z - mu) * rstd * gm1.z + bt1.z;
  y[7] = (v1.w - mu) * rstd * gm1.w + bt1.w;

  short8 pk;
#pragma unroll
  for (int i = 0; i < 8; i++) {
    __hip_bfloat16 hh = __float2bfloat16(y[i]);
    pk[i] = *(short*)&hh;
  }
  *(short8*)&xout[(size_t)row * SIXH + cbase] = pk;
}

// ---------------------------------------------------------------------------
// GEMM1: R9 version verbatim (best measured: 102.6us, FETCH 64.7MB,
// 0 bank conflicts). Persistent, XCD-sibling-grouped, 256x256 tile, BK=64,
// 8 waves, 2-barrier K-loop, counted vmcnt(4), XOR-swizzled LDS.
// ---------------------------------------------------------------------------
__global__ __launch_bounds__(512, 2)
void gemm1_8ph(const __hip_bfloat16* __restrict__ A,
               const __hip_bfloat16* __restrict__ Bt,
               const float* __restrict__ bias,
               __hip_bfloat16* __restrict__ out,
               const int* __restrict__ total_ptr) {
  constexpr int K = SIXH;     // 1536
  constexpr int NT = K / 64;  // 24 K-tiles
  constexpr int N = FOURH;    // 1024

  extern __shared__ __align__(16) char lds[];

  int total = total_ptr[0];
  int padded = (total + 255) & ~255;
  int num_mt = padded >> 8;

  int bid = blockIdx.x;        // 0..255
  int xcd = bid & 7;
  int slot = bid >> 3;         // 0..31
  int nt = slot & 3;           // 0..3
  int mtb = slot >> 2;         // 0..7
  int n0 = nt * 256;

  int tid = threadIdx.x;
  int lane = tid & 63;
  int w = tid >> 6;
  int wave_m = w >> 2;
  int wave_n = w & 3;

  int r15 = lane & 15, g = lane >> 4;
  int slot_r = (((r15 & 1) << 2) | g) ^ (r15 >> 1);
  int lane_off = (r15 >> 1) * 128 + slot_r * 16;

  int s0 = (tid & 7) ^ ((tid >> 3) & 7);
  int scol = (s0 & 3) * 8;
  int row0 = ((tid >> 3) << 1) + (s0 >> 2);
  int ldst0 = w * 1024;

  float bv4[4];
#pragma unroll
  for (int ni = 0; ni < 4; ni++)
    bv4[ni] = bias[n0 + wave_n * 64 + ni * 16 + r15];

#define REGA(d, h) (lds + (d) * 65536 + (h) * 16384)
#define REGB(d, h) (lds + (d) * 65536 + 32768 + (h) * 16384)

#define STAGE(P, t0, kt, h, rb)                                                \
  do {                                                                         \
    __builtin_amdgcn_global_load_lds(                                          \
        (gbl_void*)((P) + (size_t)((t0) + row0) * K + (kt) * 64 + (h) * 32 +   \
                    scol),                                                     \
        (lds_void*)((rb) + ldst0), 16, 0, 0);                                  \
    __builtin_amdgcn_global_load_lds(                                          \
        (gbl_void*)((P) + (size_t)((t0) + row0 + 128) * K + (kt) * 64 +        \
                    (h) * 32 + scol),                                          \
        (lds_void*)((rb) + 8192 + ldst0), 16, 0, 0);                           \
  } while (0)

  for (int mt = xcd + 8 * mtb; mt < num_mt; mt += 64) {
    int m0 = mt * 256;

    f32x4 acc[8][4] = {};

    STAGE(A, m0, 0, 0, REGA(0, 0));
    STAGE(Bt, n0, 0, 0, REGB(0, 0));
    STAGE(A, m0, 0, 1, REGA(0, 1));
    STAGE(Bt, n0, 0, 1, REGB(0, 1));
    STAGE(A, m0, 1, 0, REGA(1, 0));
    STAGE(Bt, n0, 1, 0, REGB(1, 0));
    VMCNT4();
    ASM_BAR();

    for (int kt = 0; kt < NT; ++kt) {
      int d = kt & 1;
      int kc1 = (kt + 1 < NT) ? kt + 1 : NT - 1;
      int kc2 = (kt + 2 < NT) ? kt + 2 : NT - 1;
      char* A0 = REGA(d, 0); char* A1 = REGA(d, 1);
      char* B0 = REGB(d, 0); char* B1 = REGB(d, 1);
      char* An1 = REGA(d ^ 1, 1);
      char* Bn1 = REGB(d ^ 1, 1);

      short8 a[4], b[4];

      // ======== first half: kh0 (reads A0/B0; stages next-dbuf kh1) ========
#pragma unroll
      for (int ni = 0; ni < 4; ni++)
        b[ni] = *(const short8*)(B0 + (wave_n * 64 + ni * 16) * 64 + lane_off);
#pragma unroll
      for (int j = 0; j < 4; j++)
        a[j] = *(const short8*)(A0 + (wave_m * 128 + j * 16) * 64 + lane_off);
      STAGE(A, m0, kc1, 1, An1);
      __builtin_amdgcn_s_setprio(1);
#pragma unroll
      for (int j = 0; j < 4; j++)
#pragma unroll
        for (int ni = 0; ni < 4; ni++)
          acc[j][ni] = __builtin_amdgcn_mfma_f32_16x16x32_bf16(a[j], b[ni],
                                                               acc[j][ni], 0, 0, 0);
      __builtin_amdgcn_s_setprio(0);
#pragma unroll
      for (int j = 0; j < 4; j++)
        a[j] = *(const short8*)(A0 + (wave_m * 128 + (4 + j) * 16) * 64 + lane_off);
      STAGE(Bt, n0, kc1, 1, Bn1);
      __builtin_amdgcn_s_setprio(1);
#pragma unroll
      for (int j = 0; j < 4; j++)
#pragma unroll
        for (int ni = 0; ni < 4; ni++)
          acc[4 + j][ni] = __builtin_amdgcn_mfma_f32_16x16x32_bf16(
              a[j], b[ni], acc[4 + j][ni], 0, 0, 0);
      __builtin_amdgcn_s_setprio(0);
      ASM_BAR();  // bar_mid

      // ======== second half: kh1 (reads A1/B1; stages this-dbuf kh0) =======
#pragma unroll
      for (int ni = 0; ni < 4; ni++)
        b[ni] = *(const short8*)(B1 + (wave_n * 64 + ni * 16) * 64 + lane_off);
#pragma unroll
      for (int j = 0; j < 4; j++)
        a[j] = *(const short8*)(A1 + (wave_m * 128 + j * 16) * 64 + lane_off);
      STAGE(A, m0, kc2, 0, A0);
      __builtin_amdgcn_s_setprio(1);
#pragma unroll
      for (int j = 0; j < 4; j++)
#pragma unroll
        for (int ni = 0; ni < 4; ni++)
          acc[j][ni] = __builtin_amdgcn_mfma_f32_16x16x32_bf16(a[j], b[ni],
                                                               acc[j][ni], 0, 0, 0);
      __builtin_amdgcn_s_setprio(0);
#pragma unroll
      for (int j = 0; j < 4; j++)
        a[j] = *(const short8*)(A1 + (wave_m * 128 + (4 + j) * 16) * 64 + lane_off);
      STAGE(Bt, n0, kc2, 0, B0);
      __builtin_amdgcn_s_setprio(1);
#pragma unroll
      for (int j = 0; j < 4; j++)
#pragma unroll
        for (int ni = 0; ni < 4; ni++)
          acc[4 + j][ni] = __builtin_amdgcn_mfma_f32_16x16x32_bf16(
              a[j], b[ni], acc[4 + j][ni], 0, 0, 0);
      __builtin_amdgcn_s_setprio(0);
      VMCNT4();
      ASM_BAR();  // bar_end
    }
    VMCNT0();

    int r0 = g * 4;
#pragma unroll
    for (int mi = 0; mi < 8; mi++)
#pragma unroll
      for (int ni = 0; ni < 4; ni++) {
        int col = n0 + wave_n * 64 + ni * 16 + r15;
        float bv = bv4[ni];
#pragma unroll
        for (int r = 0; r < 4; r++) {
          int row = m0 + wave_m * 128 + mi * 16 + r0 + r;
          float v = acc[mi][ni][r] + bv;
          v = v / (1.0f + __expf(-v));  // silu
          out[(size_t)row * N + col] = __float2bfloat16(v);
        }
      }
  }
#undef STAGE
#undef REGA
#undef REGB
}

// ---------------------------------------------------------------------------
// GEMM2 wide (R12 verbatim): 128 rows x full N=256, 8 waves of 64x64,
// fused scatter epilogue into d_out.
// ---------------------------------------------------------------------------
__global__ __launch_bounds__(512, 2)
void gemm2_wide(const __hip_bfloat16* __restrict__ A,
                const __hip_bfloat16* __restrict__ Bt,
                const float* __restrict__ bias,
                const int* __restrict__ tpos,
                const float* __restrict__ pos_emb,
                float* __restrict__ out,
                const int* __restrict__ total_ptr) {
  constexpr int K = FOURH;  // 1024
  int m0 = blockIdx.x * 128;
  int total = total_ptr[0];
  int padded = (total + 127) & ~127;
  if (m0 >= padded) return;

  __shared__ __hip_bfloat16 As[128 * 64];  // 16KB
  __shared__ __hip_bfloat16 Bs[256 * 64];  // 32KB
  int tid = threadIdx.x;
  int lane = tid & 63, w = tid >> 6;
  int wave_m = w >> 2;  // 0..1
  int wave_n = w & 3;   // 0..3
  int wm = wave_m * 64, wn = wave_n * 64;

  int srow = lane >> 3;
  int scol = (lane & 7) * 8;
  int r15 = lane & 15, g = lane >> 4;

  f32x4 acc[4][4] = {};

  for (int k0 = 0; k0 < K; k0 += 64) {
#pragma unroll
    for (int i = 0; i < 2; i++) {
      int c = w * 2 + i;
      int row = c * 8 + srow;
      __builtin_amdgcn_global_load_lds(
          (gbl_void*)&A[(size_t)(m0 + row) * K + k0 + scol],
          (lds_void*)(As + c * 512), 16, 0, 0);
    }
#pragma unroll
    for (int i = 0; i < 4; i++) {
      int c = w * 4 + i;
      int row = c * 8 + srow;
      __builtin_amdgcn_global_load_lds(
          (gbl_void*)&Bt[(size_t)row * K + k0 + scol],
          (lds_void*)(Bs + c * 512), 16, 0, 0);
    }
    __syncthreads();
#pragma unroll
    for (int kk = 0; kk < 64; kk += 32) {
      short8 a[4], bb[4];
#pragma unroll
      for (int m = 0; m < 4; m++)
        a[m] = *(const short8*)&As[(wm + m * 16 + r15) * 64 + kk + 8 * g];
#pragma unroll
      for (int n = 0; n < 4; n++)
        bb[n] = *(const short8*)&Bs[(wn + n * 16 + r15) * 64 + kk + 8 * g];
#pragma unroll
      for (int m = 0; m < 4; m++)
#pragma unroll
        for (int n = 0; n < 4; n++)
          acc[m][n] = __builtin_amdgcn_mfma_f32_16x16x32_bf16(a[m], bb[n],
                                                              acc[m][n], 0, 0, 0);
    }
    __syncthreads();
  }

  int r0 = g * 4;
#pragma unroll
  for (int m = 0; m < 4; m++) {
#pragma unroll
    for (int r = 0; r < 4; r++) {
      int row = m0 + wm + m * 16 + r0 + r;
      if (row >= total) continue;
      int pa = tpos[row];
      if (pa < 0) continue;
      int p = pa & (MAXT - 1);
#pragma unroll
      for (int n = 0; n < 4; n++) {
        int col = wn + n * 16 + r15;
        float v = acc[m][n][r] + bias[col] + pos_emb[p * H_ + col];
        out[(size_t)pa * H_ + col] = v;
      }
    }
  }
}

// ---------------------------------------------------------------------------
// merge2: sep rows (sep_token + pos_emb), zero-fill empty positions, mm.
// ---------------------------------------------------------------------------
__global__ void merge2_kernel(const int* __restrict__ gids,
                              const int* __restrict__ lengths,
                              const float* __restrict__ sep_token,
                              const float* __restrict__ pos_emb,
                              float* __restrict__ out) {
  int b = blockIdx.x, t = threadIdx.x;
  __shared__ signed char src[MAXT];
  __shared__ int g[L_];
  __shared__ int sh_total;
  int len = lengths[b];
  src[t] = 0;
  for (int l = t; l < len; l += 256) g[l] = gids[b * L_ + l];
  __syncthreads();
  if (t == 0) {
    int nsep = 0;
    for (int l = 0; l + 1 < len; l++)
      if (g[l] != g[l + 1]) nsep++;
    int total = len + nsep;
    sh_total = total;
    int off = MAXT - total;
    int sb = 0;
    for (int l = 0; l < len; l++) {
      int ti = off + l + sb;
      if (ti >= 0) src[ti] = 2;
      if (l + 1 < len && g[l] != g[l + 1]) {
        if (ti + 1 >= 0) src[ti + 1] = 1;
        sb++;
      }
    }
  }
  __syncthreads();
  int total = sh_total;
  int mlen = min(total, MAXT);

  int q = t >> 6, lane = t & 63, c4 = lane * 4;
  float4 sep4 = *(const float4*)&sep_token[c4];
  float* orow = out + (size_t)b * MAXT * H_;
  for (int p0 = 0; p0 < MAXT; p0 += 4) {
    int p = p0 + q;
    int s = src[p];
    if (s == 2) continue;
    float4 v;
    if (s == 1) {
      float4 pe = *(const float4*)&pos_emb[p * H_ + c4];
      v.x = sep4.x + pe.x; v.y = sep4.y + pe.y;
      v.z = sep4.z + pe.z; v.w = sep4.w + pe.w;
    } else {
      v.x = 0.f; v.y = 0.f; v.z = 0.f; v.w = 0.f;
    }
    *(float4*)&orow[(size_t)p * H_ + c4] = v;
  }
  float* mm = out + (size_t)B_ * MAXT * H_;
  mm[b * MAXT + t] = (t >= MAXT - mlen) ? 1.0f : 0.0f;
}

// ---------------------------------------------------------------------------
// launch
// ---------------------------------------------------------------------------
extern "C" void kernel_launch(void* const* d_in, const int* in_sizes, int n_in,
                              void* d_out, int out_size, void* d_ws,
                              size_t ws_size, hipStream_t stream) {
  const int* tok0 = (const int*)d_in[0];
  const int* tok1 = (const int*)d_in[1];
  const int* tok2 = (const int*)d_in[2];
  const int* tok3 = (const int*)d_in[3];
  const int* tgap = (const int*)d_in[4];
  const int* gid  = (const int*)d_in[5];
  const int* lengths = (const int*)d_in[6];
  const float* token_emb = (const float*)d_in[7];
  const float* gamma = (const float*)d_in[8];
  const float* beta  = (const float*)d_in[9];
  const float* w1 = (const float*)d_in[10];
  const float* b1 = (const float*)d_in[11];
  const float* w2 = (const float*)d_in[12];
  const float* b2 = (const float*)d_in[13];
  const float* tg_emb = (const float*)d_in[14];
  const float* g_emb  = (const float*)d_in[15];
  const float* pos_emb = (const float*)d_in[16];
  const float* sep_tok = (const float*)d_in[17];

  // workspace layout (bytes) — R12 layout restored:
  //   x     bf16 [<=51200][1536] @ 0          (157,286,400)
  //   h     bf16 [<=51200][1024] @ 157286400  (104,857,600)
  //   w1t   bf16 [1024][1536]    @ 262144000  (  3,145,728)
  //   w2t   bf16 [256][1024]     @ 265289728  (    524,288)
  //   offsets int[257]           @ 265814016  (      1,028)
  //   tpos  int  [<=51200]       @ 265815044  (    204,800)
  const size_t NEEDED = 266019844;
  if (ws_size < NEEDED) return;

  char* ws = (char*)d_ws;
  __hip_bfloat16* x = (__hip_bfloat16*)ws;
  __hip_bfloat16* h = (__hip_bfloat16*)(ws + 157286400);
  __hip_bfloat16* w1t = (__hip_bfloat16*)(ws + 262144000);
  __hip_bfloat16* w2t = (__hip_bfloat16*)(ws + 265289728);
  int* offsets = (int*)(ws + 265814016);
  int* tpos = (int*)(ws + 265815044);

  fused_pre_tr<<<2048, 256, 0, stream>>>(lengths, gid, offsets, tpos, x, w1,
                                         w1t, w2, w2t);

  embed_ln_kernel<<<dim3(L_, B_), 192, 0, stream>>>(
      tok0, tok1, tok2, tok3, tgap, gid, lengths, offsets, token_emb, tg_emb,
      g_emb, gamma, beta, x);

  hipFuncSetAttribute((const void*)gemm1_8ph,
                      hipFuncAttributeMaxDynamicSharedMemorySize, 131072);
  gemm1_8ph<<<256, 512, 131072, stream>>>(x, w1t, b1, h, offsets + B_);

  gemm2_wide<<<NPOS / 128, 512, 0, stream>>>(h, w2t, b2, tpos, pos_emb,
                                             (float*)d_out, offsets + B_);

  merge2_kernel<<<B_, 256, 0, stream>>>(gid, lengths, sep_tok, pos_emb,
                                        (float*)d_out);
}